// Round 11
// baseline (53.623 us; speedup 1.0000x reference)
//
#include <hip/hip_runtime.h>

#define N 8192
#define D 128

typedef __attribute__((ext_vector_type(8))) short bf16x8;
typedef __attribute__((ext_vector_type(4))) float f32x4;
typedef unsigned int u32;
typedef unsigned short u16;

__device__ __forceinline__ u16 f2bf(float f) {
    u32 u = __float_as_uint(f);
    u += 0x7FFF + ((u >> 16) & 1);   // round-to-nearest-even
    return (u16)(u >> 16);
}

// async global->LDS, 16B/lane; dst base wave-uniform (HW adds lane*16)
__device__ __forceinline__ void gl_lds16(const u16* g, u16* l) {
    __builtin_amdgcn_global_load_lds(
        (const __attribute__((address_space(1))) u32*)g,
        (__attribute__((address_space(3))) u32*)l, 16, 0, 0);
}

// ---- kernel 1: streaming bf16 copy + row sqnorm + init ---------------------
__global__ __launch_bounds__(256) void k_prep(const float* __restrict__ x,
                                              u16* __restrict__ xbf,
                                              float* __restrict__ sq,
                                              u32* __restrict__ minkey,
                                              u32* __restrict__ ctr) {
    const int tid = threadIdx.x;
    const int r = blockIdx.x * 16 + (tid >> 4);
    const int lr = tid & 15;
    const float4* src = (const float4*)(x + (size_t)r * D + lr * 8);
    float4 v0 = src[0], v1 = src[1];
    union { u16 h[8]; uint4 v; } o;
    o.h[0] = f2bf(v0.x); o.h[1] = f2bf(v0.y); o.h[2] = f2bf(v0.z); o.h[3] = f2bf(v0.w);
    o.h[4] = f2bf(v1.x); o.h[5] = f2bf(v1.y); o.h[6] = f2bf(v1.z); o.h[7] = f2bf(v1.w);
    *(uint4*)(xbf + (size_t)r * D + lr * 8) = o.v;
    float s = v0.x * v0.x + v0.y * v0.y + v0.z * v0.z + v0.w * v0.w
            + v1.x * v1.x + v1.y * v1.y + v1.z * v1.z + v1.w * v1.w;
    s += __shfl_xor(s, 1); s += __shfl_xor(s, 2);
    s += __shfl_xor(s, 4); s += __shfl_xor(s, 8);
    if (lr == 0) { sq[r] = s; minkey[r] = 0xFFFFFFFFu; }
    if (blockIdx.x == 0 && tid < 64) ctr[tid] = 0;
}

// ---- kernel 2: A in regs, B dbuf LDS; 4-wave blocks, 2 blocks/CU -----------
// grid (64,16): block = rows [bi*128,+128) x cols [cg*512,+512).
// 4 waves as 2x2 (wave tile 64x64 per 128-col B tile). LDS = 64KB (B only).
// NO __threadfence: agent-scope fence = buffer_wbl2+inv = nukes the XCD L2
// (R5-R9 regression, +20us). Cross-block visibility via device-scope atomics.
__global__ __launch_bounds__(256, 2) void k_neg(const u16* __restrict__ xbf,
                                                const float* __restrict__ sq,
                                                u32* __restrict__ minkey,
                                                u32* __restrict__ ap2,
                                                u32* __restrict__ ctr,
                                                float* __restrict__ out) {
    __shared__ __align__(16) u16 Bl[2][128 * 128];   // 2 x 32 KB
    __shared__ u32 sflag;

    const int bi = blockIdx.x;          // 128-row panel
    const int cg = blockIdx.y;          // 512-col group
    const int row0 = bi * 128, col00 = cg * 512;
    const int tid = threadIdx.x;
    const int lane = tid & 63, wave = tid >> 6;      // 4 waves
    const int lr = lane & 15, lg = lane >> 4;
    const int wr = wave >> 1, wc = wave & 1;         // 2x2 wave grid
    const float INF = __int_as_float(0x7F800000);

    // diagonal tile for this wave's 64-row block g64 (cols g64*64):
    const int g64 = bi * 2 + wr;
    const int tdiag = (cg == (g64 >> 3) && wc == (g64 & 1)) ? ((g64 & 7) >> 1) : -1;

    // stage B tile 0: 32KB = 32 wave-issues, 8 per wave (pre-swizzled source)
#pragma unroll
    for (int it = 0; it < 8; ++it) {
        const int rb0 = wave * 32 + it * 4;
        const int r = rb0 + (lane >> 4);
        gl_lds16(xbf + (size_t)(col00 + r) * D + ((lr ^ (r & 7)) * 8),
                 Bl[0] + rb0 * 128);
    }

    // A fragments register-resident: this wave's 64 rows x 128 K (64 VGPR)
    bf16x8 af[4][4];
#pragma unroll
    for (int f = 0; f < 4; ++f)
#pragma unroll
        for (int kk = 0; kk < 4; ++kk)
            af[f][kk] = *(const bf16x8*)(xbf +
                (size_t)(row0 + wr * 64 + f * 16 + lr) * D + kk * 32 + lg * 8);
#pragma unroll
    for (int f = 0; f < 4; ++f)
#pragma unroll
        for (int kk = 0; kk < 4; ++kk)
            asm volatile("" : "+v"(af[f][kk]));   // pin vs rematerialization

    float rmin[4][4] = {{INF, INF, INF, INF}, {INF, INF, INF, INF},
                        {INF, INF, INF, INF}, {INF, INF, INF, INF}};

    __syncthreads();   // B0 resident

#pragma unroll
    for (int t = 0; t < 4; ++t) {
        const int c0 = col00 + t * 128;
        if (t + 1 < 4) {   // prefetch next B tile before compute
            const int c0n = c0 + 128;
#pragma unroll
            for (int it = 0; it < 8; ++it) {
                const int rb0 = wave * 32 + it * 4;
                const int r = rb0 + (lane >> 4);
                gl_lds16(xbf + (size_t)(c0n + r) * D + ((lr ^ (r & 7)) * 8),
                         Bl[(t + 1) & 1] + rb0 * 128);
            }
        }

        float sjv[4];
#pragma unroll
        for (int fj = 0; fj < 4; ++fj)
            sjv[fj] = sq[c0 + wc * 64 + fj * 16 + lr];

        const u16* Bp = Bl[t & 1];
        f32x4 acc[4][4] = {};
#pragma unroll
        for (int kk = 0; kk < 4; ++kk) {
            const int kx = (kk * 64 + lg * 16) ^ ((lr & 7) << 4);
            bf16x8 bq[4];
#pragma unroll
            for (int fj = 0; fj < 4; ++fj)
                bq[fj] = *(const bf16x8*)((const char*)Bp +
                         (wc * 64 + fj * 16 + lr) * 256 + kx);
#pragma unroll
            for (int fi = 0; fi < 4; ++fi)
#pragma unroll
                for (int fj = 0; fj < 4; ++fj)
                    acc[fi][fj] = __builtin_amdgcn_mfma_f32_16x16x32_bf16(
                        af[fi][kk], bq[fj], acc[fi][fj], 0, 0, 0);
        }

        if (t == tdiag) {
#pragma unroll
            for (int fi = 0; fi < 4; ++fi) {
                float rmx[4] = {-INF, -INF, -INF, -INF};
#pragma unroll
                for (int jj = 0; jj < 4; ++jj)
#pragma unroll
                    for (int fj = 0; fj < 4; ++fj) {
                        float v = fmaf(-2.f, acc[fi][fj][jj], sjv[fj]);
                        if (fj == fi) rmx[jj] = fmaxf(rmx[jj], v);
                        else rmin[fi][jj] = fminf(rmin[fi][jj], v);
                    }
#pragma unroll
                for (int jj = 0; jj < 4; ++jj) {
                    float v = rmx[jj];
                    v = fmaxf(v, __shfl_xor(v, 1));
                    v = fmaxf(v, __shfl_xor(v, 2));
                    v = fmaxf(v, __shfl_xor(v, 4));
                    v = fmaxf(v, __shfl_xor(v, 8));
                    if (lr == 0) {
                        const int gi = row0 + wr * 64 + fi * 16 + lg * 4 + jj;
                        // device-scope atomic store: visible cross-XCD, no fence
                        atomicExch(&ap2[gi], __float_as_uint(fmaxf(sq[gi] + v, 0.f)));
                    }
                }
            }
        } else {
#pragma unroll
            for (int fi = 0; fi < 4; ++fi)
#pragma unroll
                for (int jj = 0; jj < 4; ++jj)
#pragma unroll
                    for (int fj = 0; fj < 4; ++fj)
                        rmin[fi][jj] = fminf(rmin[fi][jj],
                                             fmaf(-2.f, acc[fi][fj][jj], sjv[fj]));
        }

        __syncthreads();   // drains next-tile staging + read fence
    }

    // per-wave reduce + one atomicMin per row
#pragma unroll
    for (int fi = 0; fi < 4; ++fi)
#pragma unroll
        for (int jj = 0; jj < 4; ++jj) {
            float v = rmin[fi][jj];
            v = fminf(v, __shfl_xor(v, 1));
            v = fminf(v, __shfl_xor(v, 2));
            v = fminf(v, __shfl_xor(v, 4));
            v = fminf(v, __shfl_xor(v, 8));
            if (lr == 0) {
                const int gi = row0 + wr * 64 + fi * 16 + lg * 4 + jj;
                atomicMin(&minkey[gi], __float_as_uint(fmaxf(sq[gi] + v, 0.f)));
            }
        }

    // fused finalization: last of the 16 blocks for this row panel writes out.
    // __syncthreads drains all waves' atomics (vmcnt 0) before the ctr bump.
    __syncthreads();
    if (tid == 0) sflag = atomicAdd(&ctr[bi], 1u);
    __syncthreads();
    if (sflag == 15u && tid < 128) {
        const int gi = row0 + tid;
        u32 mk = atomicAdd(&minkey[gi], 0u);   // device-scope atomic read
        u32 ab = atomicOr(&ap2[gi], 0u);       // device-scope atomic read
        out[gi] = fmaxf(sqrtf(__uint_as_float(ab)) - sqrtf(__uint_as_float(mk)) + 1.f,
                        0.f);
    }
}

extern "C" void kernel_launch(void* const* d_in, const int* in_sizes, int n_in,
                              void* d_out, int out_size, void* d_ws, size_t ws_size,
                              hipStream_t stream) {
    const float* x = (const float*)d_in[0];
    float* out = (float*)d_out;

    char* ws = (char*)d_ws;
    u16* xbf = (u16*)ws;                                // 2 MB bf16 copy
    float* sq = (float*)(ws + 2097152);                 // 32 KB
    u32* minkey = (u32*)(ws + 2097152 + 32768);         // 32 KB
    u32* ap2 = (u32*)(ws + 2097152 + 65536);            // 32 KB
    u32* ctr = (u32*)(ws + 2097152 + 98304);            // 256 B

    k_prep<<<N / 16, 256, 0, stream>>>(x, xbf, sq, minkey, ctr);
    k_neg<<<dim3(64, 16), 256, 0, stream>>>(xbf, sq, minkey, ap2, ctr, out);
}